// Round 9
// baseline (1620.114 us; speedup 1.0000x reference)
//
#include <hip/hip_runtime.h>

using v8bf  = __bf16 __attribute__((ext_vector_type(8)));
using v16f  = float  __attribute__((ext_vector_type(16)));

#define EPS_BN 1e-5f
#define ATT_SCALE 0.044194173824159216f   // 512^-0.5
#define KSPLIT 2                          // key-halves per block (intra-block wave split)

__device__ __forceinline__ unsigned short f2bf(float f){
  union { float f; unsigned int u; } c; c.f = f;
  unsigned int u = c.u + 0x7fffu + ((c.u >> 16) & 1u);
  return (unsigned short)(u >> 16);
}

__device__ __forceinline__ v8bf ld8(const unsigned short* p){
  union { uint4 u; v8bf v; } c;
  c.u = *(const uint4*)p;
  return c.v;
}

// async global->LDS, 16B per lane; LDS dest = uniform base + lane*16
__device__ __forceinline__ void glds16(const unsigned short* g, unsigned short* l){
  __builtin_amdgcn_global_load_lds(
      (const __attribute__((address_space(1))) void*)g,
      (__attribute__((address_space(3))) void*)l, 16, 0, 0);
}

// ---------------- cast fp32 -> bf16 (8 elems/thread) ----------------
__global__ void cast_bf16_kernel(const float* __restrict__ src,
                                 unsigned short* __restrict__ dst, int n8){
  int i = blockIdx.x * 256 + threadIdx.x;
  if (i >= n8) return;
  const float4* s4 = (const float4*)src;
  float4 a = s4[2*i], b = s4[2*i+1];
  union { unsigned short s[8]; uint4 u; } r;
  r.s[0]=f2bf(a.x); r.s[1]=f2bf(a.y); r.s[2]=f2bf(a.z); r.s[3]=f2bf(a.w);
  r.s[4]=f2bf(b.x); r.s[5]=f2bf(b.y); r.s[6]=f2bf(b.z); r.s[7]=f2bf(b.w);
  ((uint4*)dst)[i] = r.u;
}

// ---------------- BN affine precompute ----------------
__global__ void bn_precompute(const float* __restrict__ g, const float* __restrict__ be,
                              const float* __restrict__ mn, const float* __restrict__ vr,
                              float* __restrict__ scale, float* __restrict__ shift,
                              int n, int qfold){
  int i = blockIdx.x * 256 + threadIdx.x;
  if (i >= n) return;
  float s = g[i] * rsqrtf(vr[i] + EPS_BN);
  float t = be[i] - mn[i] * s;
  if (qfold && (i & 1023) < 256){ s *= ATT_SCALE; t *= ATT_SCALE; }
  scale[i] = s; shift[i] = t;
}

// ---------------- generic NT GEMM, 128x128 tile, BK=64, global_load_lds ----
// [R7-proven single-buffer structure — R8's explicit dbuf regressed (LDS 2x ->
// occupancy halved); implicit wave-level overlap already covers the prefetch]
// LDS: [row][8 granules of 8 halves], slot s of row r holds granule s ^ (r&7)
// MODE 0: qkv projection, BN epilogue. Q/K column-blocks -> row-major bf16 qkv
//         [M][8192]; V column-blocks (bx&4) -> TRANSPOSED via LDS bounce
//         directly into Vt [bh][512][1024] (replaces the transpose_v kernel).
// MODE 1: PV, *inv(sum of KSPLIT partials) + clamp epilogue -> outc bf16
// MODE 3: proj split-K (blockIdx.z = split of 4) -> fp32 partials [4][Mtot][512]
template<int MODE>
__launch_bounds__(256, 2)
__global__ void gemm_nt(const unsigned short* __restrict__ A,
                        const unsigned short* __restrict__ Bm,
                        int K, long sA, long sB, long mbase,   // mbase = Mtot for MODE 3
                        const float* __restrict__ scale, const float* __restrict__ shift,
                        const float* __restrict__ sums,        // MODE 1: [bh][KSPLIT][1024] partials
                        unsigned short* __restrict__ ob16,
                        float* __restrict__ outf,
                        unsigned short* __restrict__ vt)       // MODE 0: Vt base
{
  __shared__ __align__(16) unsigned short Sh[16384];  // As(8192) + Bs(8192), 32 KB
  unsigned short* As = Sh;
  unsigned short* Bs = Sh + 8192;
  const int tid = threadIdx.x;
  const int w = tid >> 6, lane = tid & 63, ln = lane & 31, lg = lane >> 5;
  const int wm = (w >> 1) * 64, wn = (w & 1) * 64;
  const long bm = (long)blockIdx.y * 128, bn = (long)blockIdx.x * 128;
  const int z = blockIdx.z;
  const unsigned short* Ab = A + (MODE == 3 ? 0L : (long)z * sA) + bm * K;
  const unsigned short* Bb = Bm + (MODE == 3 ? 0L : (long)z * sB) + bn * K;

  const int kbeg = (MODE == 3) ? z * (K >> 2) : 0;
  const int kend = (MODE == 3) ? kbeg + (K >> 2) : K;

  // staging: wave w covers tile rows [w*32, w*32+32), 4 instrs/matrix (8 rows each)
  const int rsub = lane >> 3;            // 0..7
  const int gsl  = lane & 7;             // granule slot 0..7
  const unsigned short* gA[4]; const unsigned short* gB[4];
  unsigned short *lA[4], *lB[4];
  #pragma unroll
  for (int i = 0; i < 4; i++){
    int r = w*32 + i*8 + rsub;
    int go = (gsl ^ (r & 7)) * 8;        // global granule offset (halves)
    gA[i] = Ab + (long)r * K + go;
    gB[i] = Bb + (long)r * K + go;
    lA[i] = As + (w*32 + i*8) * 64;
    lB[i] = Bs + (w*32 + i*8) * 64;
  }

  v16f acc[2][2];
  #pragma unroll
  for (int a = 0; a < 2; a++)
    #pragma unroll
    for (int b = 0; b < 2; b++)
      #pragma unroll
      for (int i = 0; i < 16; i++) acc[a][b][i] = 0.f;

  for (int k0 = kbeg; k0 < kend; k0 += 64){
    __syncthreads();
    #pragma unroll
    for (int i = 0; i < 4; i++){
      glds16(gA[i] + k0, lA[i]);
      glds16(gB[i] + k0, lB[i]);
    }
    __syncthreads();
    #pragma unroll
    for (int kk = 0; kk < 4; kk++){     // granule-pair index: gd = kk*2 + lg
      v8bf af[2], bfr[2];
      #pragma unroll
      for (int t = 0; t < 2; t++){
        int Ra = wm + t*32 + ln;
        af[t] = *(const v8bf*)&As[Ra*64 + ((kk*2 + lg) ^ (Ra & 7))*8];
        int Rb = wn + t*32 + ln;
        bfr[t] = *(const v8bf*)&Bs[Rb*64 + ((kk*2 + lg) ^ (Rb & 7))*8];
      }
      #pragma unroll
      for (int tm = 0; tm < 2; tm++)
        #pragma unroll
        for (int tn = 0; tn < 2; tn++)
          acc[tm][tn] = __builtin_amdgcn_mfma_f32_32x32x16_bf16(af[tm], bfr[tn], acc[tm][tn], 0, 0, 0);
    }
  }

  // ---- MODE 0, V column-block: BN + transpose via LDS bounce -> Vt ----
  if (MODE == 0 && (blockIdx.x & 4)){
    __syncthreads();                       // all waves done reading As/Bs
    unsigned short* Ts = Sh;               // 128 cols x 128 rows bf16, XOR-swizzled
    #pragma unroll
    for (int tm = 0; tm < 2; tm++){
      #pragma unroll
      for (int tn = 0; tn < 2; tn++){
        int c = wn + tn*32 + ln;           // local col 0..127
        long gn = bn + c;
        float sc = scale[gn], sh = shift[gn];
        int xk = (c & 15) << 3;            // XOR key on m bits 3..6
        #pragma unroll
        for (int q = 0; q < 4; q++){
          int mq = wm + tm*32 + 8*q + 4*lg;   // 4-aligned m base
          union { unsigned short s[4]; unsigned long long u; } pk;
          #pragma unroll
          for (int j = 0; j < 4; j++)
            pk.s[j] = f2bf(acc[tm][tn][q*4 + j] * sc + sh);
          *(unsigned long long*)&Ts[c*128 + (mq ^ xk)] = pk.u;
        }
      }
    }
    __syncthreads();
    const int h  = (int)(bn >> 10);
    const int j0 = (int)(bn & 1023) - 512;    // d offset 0/128/256/384
    unsigned short* Vtb = vt + ((bm >> 10)*8 + h) * 524288L;
    const int nl0 = (int)(bm & 1023);
    #pragma unroll
    for (int i = 0; i < 8; i++){
      int idx = i*256 + tid;
      int c = idx >> 4, g = idx & 15;         // col, m-group
      uint4 u = *(const uint4*)&Ts[c*128 + ((g ^ (c & 15)) << 3)];
      *(uint4*)(Vtb + (long)(j0 + c)*1024 + nl0 + g*8) = u;
    }
    return;
  }

  float invs[2][16];
  if (MODE == 1){
    #pragma unroll
    for (int tm = 0; tm < 2; tm++)
      #pragma unroll
      for (int i = 0; i < 16; i++){
        long gm = bm + wm + tm*32 + (i&3) + 8*(i>>2) + 4*lg;
        const float* sp = sums + (long)z * (KSPLIT*1024L) + gm;
        float s = 0.f;
        #pragma unroll
        for (int kp = 0; kp < KSPLIT; kp++) s += sp[kp*1024];
        invs[tm][i] = 1.0f / s;
      }
  }

  #pragma unroll
  for (int tm = 0; tm < 2; tm++){
    #pragma unroll
    for (int tn = 0; tn < 2; tn++){
      long gn = bn + wn + tn*32 + ln;
      float sc = 0.f, sh = 0.f;
      if (MODE == 0){ sc = scale[gn]; sh = shift[gn]; }
      #pragma unroll
      for (int i = 0; i < 16; i++){
        long gm = bm + wm + tm*32 + (i&3) + 8*(i>>2) + 4*lg;
        float v = acc[tm][tn][i];
        if (MODE == 0){
          ob16[gm*8192 + gn] = f2bf(v * sc + sh);        // row-major, coalesced
        } else if (MODE == 1){
          v = v * invs[tm][i];
          v = fminf(1.f, fmaxf(-1.f, v));
          int b2 = z >> 3, hh = z & 7;
          ob16[((long)b2*1024 + gm)*4096 + hh*512 + gn] = f2bf(v);
        } else {
          outf[((long)z * mbase + gm)*512 + gn] = v;     // fp32 partial
        }
      }
    }
  }
}

// -------- reduce 4 split-K partials + BN affine -> fp32 out rows ----------
__global__ void reduce_bn(const float* __restrict__ part,
                          const float* __restrict__ sc, const float* __restrict__ sh,
                          float* __restrict__ out, long Mtot, long mbase){
  long idx = (long)blockIdx.x * 256 + threadIdx.x;     // float4 index
  if (idx >= Mtot * 128) return;
  long gm = idx >> 7;
  int gn4 = (int)(idx & 127) * 4;
  long PS = Mtot * 512;
  const float* p = part + gm*512 + gn4;
  float4 p0 = *(const float4*)(p);
  float4 p1 = *(const float4*)(p + PS);
  float4 p2 = *(const float4*)(p + 2*PS);
  float4 p3 = *(const float4*)(p + 3*PS);
  float4 s4 = *(const float4*)(sc + gn4);
  float4 h4 = *(const float4*)(sh + gn4);
  float4 r;
  r.x = (p0.x+p1.x+p2.x+p3.x)*s4.x + h4.x;
  r.y = (p0.y+p1.y+p2.y+p3.y)*s4.y + h4.y;
  r.z = (p0.z+p1.z+p2.z+p3.z)*s4.z + h4.z;
  r.w = (p0.w+p1.w+p2.w+p3.w)*s4.w + h4.w;
  *(float4*)(out + (mbase + gm)*512 + gn4) = r;
}

// ---------------- attention scores: E = exp(QK^T + bias), partial row sums --
// grid (16, 8G). Block: 256 thr = 4 waves = (m-half mh) x (key-half kh).
// Block covers 64 q-rows x ALL 1024 keys. Staging unit: 64 keys x 128 dims
// (16 KB), double-buffered -> 32 KB LDS. Register diet (a[2] chains, bias in
// epilogue) + __launch_bounds__(256,4) targets VGPR<=128 -> 4 blocks/CU
// (16 waves, 2x the 64KB version; VGPR cliff at 128 per m69).
// 32 stages: stage s = (tile t = s>>1, dim-half hf = s&1); acc carried across
// the two halves of each tile; epilogue on odd stages.
// Per-key-half rowsums -> psums[bh][2][1024]; PV (MODE 1) sums the 2 partials.
// XCD swizzle: all 16 m-blocks of one bh land on ONE XCD -> K panel + bias
// L2-resident (R2: FETCH 90->34.5 MB).
__launch_bounds__(256, 4)
__global__ void attn_scores(const unsigned short* __restrict__ qkv,
                            const float* __restrict__ bias,
                            unsigned short* __restrict__ E,
                            float* __restrict__ psums)
{
  __shared__ __align__(16) unsigned short Ks[2][64*128];   // 2 x 16 KB
  // ---- XCD-locality swizzle (bijective for gridDim.y multiple of 8) ----
  const int lid  = blockIdx.x + (blockIdx.y << 4);   // gridDim.x == 16
  const int xcd  = lid & 7;
  const int s_   = lid >> 3;
  const int mblk = s_ & 15;
  const int bh   = xcd + 8 * (s_ >> 4);
  const int b2 = bh >> 3, h = bh & 7;
  const int tid = threadIdx.x, w = tid >> 6, lane = tid & 63, ln = lane & 31, lg = lane >> 5;
  const int mh = w & 1, kh = w >> 1;
  const int m0 = mblk * 64 + mh * 32;
  const unsigned short* qbase = qkv + (long)b2*1024*8192 + h*1024;
  const unsigned short* kbase = qbase + 256;
  const float* biash = bias + (long)h * 1048576;
  unsigned short* Eb = E + (long)bh * 1048576;

  // Q fragments: A[m=ln][k = kf*16 + lg*8 + j]  (kf 0..7 dims 0..127; 8..15: 128..255)
  v8bf qf[16];
  {
    const unsigned short* qrow = qbase + (long)(m0 + ln)*8192 + lg*8;
    #pragma unroll
    for (int kf = 0; kf < 16; kf++) qf[kf] = ld8(qrow + kf*16);
  }

  const int r4  = lane >> 4;    // staging: 4 rows/instr
  const int s16 = lane & 15;    // granule slot 0..15

  float sm[16];
  #pragma unroll
  for (int i = 0; i < 16; i++) sm[i] = 0.f;

  // stage s=(t,hf): 64 keys x 128 dims into buf; wave w stages rows [w*16,+16)
  auto stage = [&](int s, int buf){
    int t = s >> 1, hf = s & 1;
    const unsigned short* src0 = kbase + (long)(t*64)*8192 + hf*128;
    #pragma unroll
    for (int i = 0; i < 4; i++){
      int row = w*16 + i*4 + r4;
      glds16(src0 + (long)row*8192 + (s16 ^ (row & 15))*8,
             &Ks[buf][(w*16 + i*4)*128]);
    }
  };

  stage(0, 0);   // prologue

  v16f a[2];

  for (int s = 0; s < 32; s++){
    __syncthreads();
    const int cb = s & 1;
    const int t = s >> 1, hf = s & 1;

    if (hf == 0){
      #pragma unroll
      for (int c = 0; c < 2; c++)
        #pragma unroll
        for (int i = 0; i < 16; i++) a[c][i] = 0.f;
    }

    if (s < 31) stage(s + 1, cb ^ 1);

    #pragma unroll
    for (int kb = 0; kb < 8; kb++){
      v8bf kf8 = *(const v8bf*)&Ks[cb][(kh*32 + ln)*128 + ((2*kb + lg) ^ (ln & 15))*8];
      a[kb & 1] = __builtin_amdgcn_mfma_f32_32x32x16_bf16(qf[hf*8 + kb], kf8, a[kb & 1], 0, 0, 0);
    }

    if (hf == 1){
      const int col = t*64 + kh*32 + ln;
      #pragma unroll
      for (int q = 0; q < 4; q++){
        #pragma unroll
        for (int j = 0; j < 4; j++){
          int i = q*4 + j;
          int r = 4*lg + 8*q + j;
          float e = __expf(a[0][i] + a[1][i] + biash[(long)(m0 + r)*1024 + col]);
          sm[i] += e;
          Eb[(long)(m0 + r)*1024 + col] = f2bf(e);
        }
      }
    }
  }

  // reduce across the wave's 32 key-lanes
  #pragma unroll
  for (int i = 0; i < 16; i++){
    #pragma unroll
    for (int d = 1; d < 32; d <<= 1) sm[i] += __shfl_xor(sm[i], d, 64);
  }
  if (ln == 0){
    float* sp = psums + ((long)bh * KSPLIT + kh)*1024 + m0 + 4*lg;
    #pragma unroll
    for (int q = 0; q < 4; q++)
      #pragma unroll
      for (int j = 0; j < 4; j++)
        sp[8*q + j] = sm[q*4 + j];
  }
}

extern "C" void kernel_launch(void* const* d_in, const int* in_sizes, int n_in,
                              void* d_out, int out_size, void* d_ws, size_t ws_size,
                              hipStream_t stream)
{
  const float* x        = (const float*)d_in[0];
  const float* qkv_w    = (const float*)d_in[1];
  const float* qg       = (const float*)d_in[2];
  const float* qb       = (const float*)d_in[3];
  const float* qm       = (const float*)d_in[4];
  const float* qv       = (const float*)d_in[5];
  const float* pos_bias = (const float*)d_in[6];
  const float* pw       = (const float*)d_in[7];
  const float* pg       = (const float*)d_in[8];
  const float* pbt      = (const float*)d_in[9];
  const float* pmn      = (const float*)d_in[10];
  const float* pvr      = (const float*)d_in[11];
  float* out = (float*)d_out;

  // ---- adaptive workspace: FIXED 16.85MB + G*43.55MB (outc/partials overlaid) ----
  const unsigned long FIXED = 16846848UL;
  const unsigned long PERG  = 43548672UL;
  long G = 1;
  if      (ws_size >= FIXED + PERG*16) G = 16;
  else if (ws_size >= FIXED + PERG*8)  G = 8;
  else if (ws_size >= FIXED + PERG*4)  G = 4;
  else if (ws_size >= FIXED + PERG*2)  G = 2;
  else if (ws_size >= FIXED + PERG)    G = 1;
  else return;

  char* ws = (char*)d_ws;
  unsigned short* wqb = (unsigned short*)(ws + 0L);            // 12,582,912
  unsigned short* wpb = (unsigned short*)(ws + 12582912L);     //  4,194,304
  float* sc_qkv       = (float*)(ws + 16777216L);              //     32,768
  float* sh_qkv       = (float*)(ws + 16809984L);              //     32,768
  float* sc_p         = (float*)(ws + 16842752L);              //      2,048
  float* sh_p         = (float*)(ws + 16844800L);              //      2,048
  const long gb = 16846848L;
  unsigned short* xbg   = (unsigned short*)(ws + gb);                      // G*1,572,864
  unsigned short* qkvg  = (unsigned short*)(ws + gb + G*1572864L);         // G*16,777,216
  unsigned short* Vtg   = (unsigned short*)(ws + gb + G*18350080L);        // G*8,388,608
  unsigned short* Eg    = (unsigned short*)(ws + gb + G*26738688L);        // G*16,777,216
  float* sumsg          = (float*)(ws + gb + G*43515904L);                 // G*32,768 (unused)
  // overlays (dead-buffer reuse):
  unsigned short* outcg = qkvg;                 // qkv region dead after attn
  float* partials       = (float*)Eg;           // E region dead after PV
  float* psums          = (float*)xbg;          // x-bf16 region dead after qkv GEMM
                                                // needs G*8*KSPLIT*1024*4 = G*64KB <= G*1.5MB
  (void)sumsg;

  // weights + BN affines (once)
  cast_bf16_kernel<<<dim3(3072), 256, 0, stream>>>(qkv_w, wqb, 786432);
  cast_bf16_kernel<<<dim3(1024), 256, 0, stream>>>(pw,    wpb, 262144);
  bn_precompute<<<dim3(32), 256, 0, stream>>>(qg, qb, qm, qv, sc_qkv, sh_qkv, 8192, 1);
  bn_precompute<<<dim3(2),  256, 0, stream>>>(pg, pbt, pmn, pvr, sc_p, sh_p, 512, 0);

  const int nG = (int)(16 / G);
  for (int g = 0; g < nG; g++){
    const float* xg = x + (long)g * G * 786432L;
    long mbase = (long)g * G * 1024L;

    cast_bf16_kernel<<<dim3((unsigned)(G*384)), 256, 0, stream>>>(xg, xbg, (int)(G*98304));

    // qkv = BN(x @ qkv_w^T) -> Q/K row-major [G*1024][8192]; V transposed -> Vt
    gemm_nt<0><<<dim3(64, (unsigned)(8*G), 1), 256, 0, stream>>>(
        xbg, wqb, 768, 0L, 0L, 0L, sc_qkv, sh_qkv, nullptr, qkvg, nullptr, Vtg);

    // E = exp(QK^T + bias), per-key-half rowsums (4 blk/CU target, XCD-swizzled)
    attn_scores<<<dim3(16, (unsigned)(8*G)), 256, 0, stream>>>(
        qkvg, pos_bias, Eg, psums);

    // outc = clamp((E @ V) / sum, -1, 1)  (overlays qkv region)
    gemm_nt<1><<<dim3(4, 8, (unsigned)(8*G)), 256, 0, stream>>>(
        Eg, Vtg, 1024, 1048576L, 524288L, 0L, nullptr, nullptr, psums, outcg, nullptr, nullptr);

    // proj split-K=4 -> fp32 partials (overlays E region)
    gemm_nt<3><<<dim3(4, (unsigned)(8*G), 4), 256, 0, stream>>>(
        outcg, wpb, 4096, 0L, 0L, (long)(G*1024), nullptr, nullptr, nullptr,
        nullptr, partials, nullptr);

    // out rows [mbase, ...) = (sum partials)*sc + sh
    reduce_bn<<<dim3((unsigned)(G*512)), 256, 0, stream>>>(
        partials, sc_p, sh_p, out, (long)(G*1024), mbase);
  }
}

// Round 10
// 961.401 us; speedup vs baseline: 1.6852x; 1.6852x over previous
//
#include <hip/hip_runtime.h>

using v8bf  = __bf16 __attribute__((ext_vector_type(8)));
using v16f  = float  __attribute__((ext_vector_type(16)));

#define EPS_BN 1e-5f
#define ATT_SCALE 0.044194173824159216f   // 512^-0.5
#define KSPLIT 2                          // key-halves per block (intra-block wave split)

__device__ __forceinline__ unsigned short f2bf(float f){
  union { float f; unsigned int u; } c; c.f = f;
  unsigned int u = c.u + 0x7fffu + ((c.u >> 16) & 1u);
  return (unsigned short)(u >> 16);
}

__device__ __forceinline__ v8bf ld8(const unsigned short* p){
  union { uint4 u; v8bf v; } c;
  c.u = *(const uint4*)p;
  return c.v;
}

// async global->LDS, 16B per lane; LDS dest = uniform base + lane*16
__device__ __forceinline__ void glds16(const unsigned short* g, unsigned short* l){
  __builtin_amdgcn_global_load_lds(
      (const __attribute__((address_space(1))) void*)g,
      (__attribute__((address_space(3))) void*)l, 16, 0, 0);
}

// ---------------- cast fp32 -> bf16 (8 elems/thread) ----------------
__global__ void cast_bf16_kernel(const float* __restrict__ src,
                                 unsigned short* __restrict__ dst, int n8){
  int i = blockIdx.x * 256 + threadIdx.x;
  if (i >= n8) return;
  const float4* s4 = (const float4*)src;
  float4 a = s4[2*i], b = s4[2*i+1];
  union { unsigned short s[8]; uint4 u; } r;
  r.s[0]=f2bf(a.x); r.s[1]=f2bf(a.y); r.s[2]=f2bf(a.z); r.s[3]=f2bf(a.w);
  r.s[4]=f2bf(b.x); r.s[5]=f2bf(b.y); r.s[6]=f2bf(b.z); r.s[7]=f2bf(b.w);
  ((uint4*)dst)[i] = r.u;
}

// ---------------- BN affine precompute ----------------
__global__ void bn_precompute(const float* __restrict__ g, const float* __restrict__ be,
                              const float* __restrict__ mn, const float* __restrict__ vr,
                              float* __restrict__ scale, float* __restrict__ shift,
                              int n, int qfold){
  int i = blockIdx.x * 256 + threadIdx.x;
  if (i >= n) return;
  float s = g[i] * rsqrtf(vr[i] + EPS_BN);
  float t = be[i] - mn[i] * s;
  if (qfold && (i & 1023) < 256){ s *= ATT_SCALE; t *= ATT_SCALE; }
  scale[i] = s; shift[i] = t;
}

// ---------------- generic NT GEMM, 128x128 tile, BK=64, global_load_lds ----
// [R7-proven single-buffer structure — R8's explicit dbuf regressed (LDS 2x ->
// occupancy halved); implicit wave-level overlap already covers the prefetch]
// LDS: [row][8 granules of 8 halves], slot s of row r holds granule s ^ (r&7)
// MODE 0: qkv projection, BN epilogue. Q/K column-blocks -> row-major bf16 qkv
//         [M][8192]; V column-blocks (bx&4) -> TRANSPOSED via LDS bounce
//         directly into Vt [bh][512][1024] (replaces the transpose_v kernel).
// MODE 1: PV, *inv(sum of KSPLIT partials) + clamp epilogue -> outc bf16.
//         XCD swizzle pins each bh's 32 blocks to ONE XCD (same XCD attn wrote
//         that bh's E to) -> E/Vt L2-resident + cross-kernel reuse.
// MODE 3: proj split-K (blockIdx.z = split of 4) -> fp32 partials [4][Mtot][512]
template<int MODE>
__launch_bounds__(256, 2)
__global__ void gemm_nt(const unsigned short* __restrict__ A,
                        const unsigned short* __restrict__ Bm,
                        int K, long sA, long sB, long mbase,   // mbase = Mtot for MODE 3
                        const float* __restrict__ scale, const float* __restrict__ shift,
                        const float* __restrict__ sums,        // MODE 1: [bh][KSPLIT][1024] partials
                        unsigned short* __restrict__ ob16,
                        float* __restrict__ outf,
                        unsigned short* __restrict__ vt)       // MODE 0: Vt base
{
  __shared__ __align__(16) unsigned short Sh[16384];  // As(8192) + Bs(8192), 32 KB
  unsigned short* As = Sh;
  unsigned short* Bs = Sh + 8192;
  const int tid = threadIdx.x;
  const int w = tid >> 6, lane = tid & 63, ln = lane & 31, lg = lane >> 5;
  const int wm = (w >> 1) * 64, wn = (w & 1) * 64;

  // block-index remap (MODE 1 only): bijective XCD-locality swizzle.
  // grid (4, 8, nz) with nz % 8 == 0. lid%8 = XCD (round-robin dispatch).
  int bxi = blockIdx.x, byi = blockIdx.y, bzi = blockIdx.z;
  if (MODE == 1){
    int lid = bxi + (byi << 2) + (bzi << 5);
    int xcd = lid & 7, s = lid >> 3;
    bxi = s & 3; byi = (s >> 2) & 7;
    bzi = xcd + 8 * (s >> 5);
  }
  const long bm = (long)byi * 128, bn = (long)bxi * 128;
  const int z = bzi;
  const unsigned short* Ab = A + (MODE == 3 ? 0L : (long)z * sA) + bm * K;
  const unsigned short* Bb = Bm + (MODE == 3 ? 0L : (long)z * sB) + bn * K;

  const int kbeg = (MODE == 3) ? z * (K >> 2) : 0;
  const int kend = (MODE == 3) ? kbeg + (K >> 2) : K;

  // staging: wave w covers tile rows [w*32, w*32+32), 4 instrs/matrix (8 rows each)
  const int rsub = lane >> 3;            // 0..7
  const int gsl  = lane & 7;             // granule slot 0..7
  const unsigned short* gA[4]; const unsigned short* gB[4];
  unsigned short *lA[4], *lB[4];
  #pragma unroll
  for (int i = 0; i < 4; i++){
    int r = w*32 + i*8 + rsub;
    int go = (gsl ^ (r & 7)) * 8;        // global granule offset (halves)
    gA[i] = Ab + (long)r * K + go;
    gB[i] = Bb + (long)r * K + go;
    lA[i] = As + (w*32 + i*8) * 64;
    lB[i] = Bs + (w*32 + i*8) * 64;
  }

  v16f acc[2][2];
  #pragma unroll
  for (int a = 0; a < 2; a++)
    #pragma unroll
    for (int b = 0; b < 2; b++)
      #pragma unroll
      for (int i = 0; i < 16; i++) acc[a][b][i] = 0.f;

  for (int k0 = kbeg; k0 < kend; k0 += 64){
    __syncthreads();
    #pragma unroll
    for (int i = 0; i < 4; i++){
      glds16(gA[i] + k0, lA[i]);
      glds16(gB[i] + k0, lB[i]);
    }
    __syncthreads();
    #pragma unroll
    for (int kk = 0; kk < 4; kk++){     // granule-pair index: gd = kk*2 + lg
      v8bf af[2], bfr[2];
      #pragma unroll
      for (int t = 0; t < 2; t++){
        int Ra = wm + t*32 + ln;
        af[t] = *(const v8bf*)&As[Ra*64 + ((kk*2 + lg) ^ (Ra & 7))*8];
        int Rb = wn + t*32 + ln;
        bfr[t] = *(const v8bf*)&Bs[Rb*64 + ((kk*2 + lg) ^ (Rb & 7))*8];
      }
      #pragma unroll
      for (int tm = 0; tm < 2; tm++)
        #pragma unroll
        for (int tn = 0; tn < 2; tn++)
          acc[tm][tn] = __builtin_amdgcn_mfma_f32_32x32x16_bf16(af[tm], bfr[tn], acc[tm][tn], 0, 0, 0);
    }
  }

  // ---- MODE 0, V column-block: BN + transpose via LDS bounce -> Vt ----
  if (MODE == 0 && (blockIdx.x & 4)){
    __syncthreads();                       // all waves done reading As/Bs
    unsigned short* Ts = Sh;               // 128 cols x 128 rows bf16, XOR-swizzled
    #pragma unroll
    for (int tm = 0; tm < 2; tm++){
      #pragma unroll
      for (int tn = 0; tn < 2; tn++){
        int c = wn + tn*32 + ln;           // local col 0..127
        long gn = bn + c;
        float sc = scale[gn], sh = shift[gn];
        int xk = (c & 15) << 3;            // XOR key on m bits 3..6
        #pragma unroll
        for (int q = 0; q < 4; q++){
          int mq = wm + tm*32 + 8*q + 4*lg;   // 4-aligned m base
          union { unsigned short s[4]; unsigned long long u; } pk;
          #pragma unroll
          for (int j = 0; j < 4; j++)
            pk.s[j] = f2bf(acc[tm][tn][q*4 + j] * sc + sh);
          *(unsigned long long*)&Ts[c*128 + (mq ^ xk)] = pk.u;
        }
      }
    }
    __syncthreads();
    const int h  = (int)(bn >> 10);
    const int j0 = (int)(bn & 1023) - 512;    // d offset 0/128/256/384
    unsigned short* Vtb = vt + ((bm >> 10)*8 + h) * 524288L;
    const int nl0 = (int)(bm & 1023);
    #pragma unroll
    for (int i = 0; i < 8; i++){
      int idx = i*256 + tid;
      int c = idx >> 4, g = idx & 15;         // col, m-group
      uint4 u = *(const uint4*)&Ts[c*128 + ((g ^ (c & 15)) << 3)];
      *(uint4*)(Vtb + (long)(j0 + c)*1024 + nl0 + g*8) = u;
    }
    return;
  }

  float invs[2][16];
  if (MODE == 1){
    #pragma unroll
    for (int tm = 0; tm < 2; tm++)
      #pragma unroll
      for (int i = 0; i < 16; i++){
        long gm = bm + wm + tm*32 + (i&3) + 8*(i>>2) + 4*lg;
        const float* sp = sums + (long)z * (KSPLIT*1024L) + gm;
        float s = 0.f;
        #pragma unroll
        for (int kp = 0; kp < KSPLIT; kp++) s += sp[kp*1024];
        invs[tm][i] = 1.0f / s;
      }
  }

  #pragma unroll
  for (int tm = 0; tm < 2; tm++){
    #pragma unroll
    for (int tn = 0; tn < 2; tn++){
      long gn = bn + wn + tn*32 + ln;
      float sc = 0.f, sh = 0.f;
      if (MODE == 0){ sc = scale[gn]; sh = shift[gn]; }
      #pragma unroll
      for (int i = 0; i < 16; i++){
        long gm = bm + wm + tm*32 + (i&3) + 8*(i>>2) + 4*lg;
        float v = acc[tm][tn][i];
        if (MODE == 0){
          ob16[gm*8192 + gn] = f2bf(v * sc + sh);        // row-major, coalesced
        } else if (MODE == 1){
          v = v * invs[tm][i];
          v = fminf(1.f, fmaxf(-1.f, v));
          int b2 = z >> 3, hh = z & 7;
          ob16[((long)b2*1024 + gm)*4096 + hh*512 + gn] = f2bf(v);
        } else {
          outf[((long)z * mbase + gm)*512 + gn] = v;     // fp32 partial
        }
      }
    }
  }
}

// -------- reduce 4 split-K partials + BN affine -> fp32 out rows ----------
__global__ void reduce_bn(const float* __restrict__ part,
                          const float* __restrict__ sc, const float* __restrict__ sh,
                          float* __restrict__ out, long Mtot, long mbase){
  long idx = (long)blockIdx.x * 256 + threadIdx.x;     // float4 index
  if (idx >= Mtot * 128) return;
  long gm = idx >> 7;
  int gn4 = (int)(idx & 127) * 4;
  long PS = Mtot * 512;
  const float* p = part + gm*512 + gn4;
  float4 p0 = *(const float4*)(p);
  float4 p1 = *(const float4*)(p + PS);
  float4 p2 = *(const float4*)(p + 2*PS);
  float4 p3 = *(const float4*)(p + 3*PS);
  float4 s4 = *(const float4*)(sc + gn4);
  float4 h4 = *(const float4*)(sh + gn4);
  float4 r;
  r.x = (p0.x+p1.x+p2.x+p3.x)*s4.x + h4.x;
  r.y = (p0.y+p1.y+p2.y+p3.y)*s4.y + h4.y;
  r.z = (p0.z+p1.z+p2.z+p3.z)*s4.z + h4.z;
  r.w = (p0.w+p1.w+p2.w+p3.w)*s4.w + h4.w;
  *(float4*)(out + (mbase + gm)*512 + gn4) = r;
}

// ---------------- attention scores: E = exp(QK^T + bias), partial row sums --
// [R7-proven version] grid (16, 8G). Block: 256 thr = 4 waves = (mh) x (kh).
// Block covers 64 q-rows x ALL 1024 keys; K tiles of 64 keys x 256 dims,
// double-buffered in LDS (2 x 32 KB), staged cooperatively by all 4 waves.
// Per-key-half rowsums -> psums[bh][2][1024]; PV (MODE 1) sums the 2 partials.
// XCD swizzle: all 16 m-blocks of one bh land on ONE XCD -> K panel + bias
// L2-resident (R2: FETCH 90->34.5 MB).
__launch_bounds__(256, 2)
__global__ void attn_scores(const unsigned short* __restrict__ qkv,
                            const float* __restrict__ bias,
                            unsigned short* __restrict__ E,
                            float* __restrict__ psums)
{
  __shared__ __align__(16) unsigned short Ks[2][64*256];   // 2 x 32 KB
  // ---- XCD-locality swizzle (bijective for gridDim.y multiple of 8) ----
  const int lid  = blockIdx.x + (blockIdx.y << 4);   // gridDim.x == 16
  const int xcd  = lid & 7;
  const int s_   = lid >> 3;
  const int mblk = s_ & 15;
  const int bh   = xcd + 8 * (s_ >> 4);
  const int b2 = bh >> 3, h = bh & 7;
  const int tid = threadIdx.x, w = tid >> 6, lane = tid & 63, ln = lane & 31, lg = lane >> 5;
  const int mh = w & 1, kh = w >> 1;
  const int m0 = mblk * 64 + mh * 32;
  const unsigned short* qbase = qkv + (long)b2*1024*8192 + h*1024;
  const unsigned short* kbase = qbase + 256;
  const float* biash = bias + (long)h * 1048576;
  unsigned short* Eb = E + (long)bh * 1048576;

  // Q fragments: A[m=ln][k = kf*16 + lg*8 + j]
  v8bf qf[16];
  {
    const unsigned short* qrow = qbase + (long)(m0 + ln)*8192 + lg*8;
    #pragma unroll
    for (int kf = 0; kf < 16; kf++) qf[kf] = ld8(qrow + kf*16);
  }

  const int rr = lane >> 5, slot = lane & 31;   // staging split: 2 rows/instr

  float sm[16];
  #pragma unroll
  for (int i = 0; i < 16; i++) sm[i] = 0.f;

  const int NT = 16;   // 1024 / 64 keys per tile

  // prologue: stage tile 0 (wave w stages tile-rows [w*16, w*16+16))
  #pragma unroll
  for (int i = 0; i < 8; i++){
    int row = w*16 + i*2 + rr;                   // 0..63
    glds16(kbase + (long)row*8192 + (slot ^ (row & 31))*8, &Ks[0][(w*16 + i*2)*256]);
  }

  for (int tt = 0; tt < NT; tt++){
    __syncthreads();
    const int cb = tt & 1;

    // bias loads FIRST (older in vmcnt order than next-tile glds -> consuming
    // bias in the epilogue leaves the glds in flight)
    const int col = tt*64 + kh*32 + ln;
    float br[16];
    #pragma unroll
    for (int q = 0; q < 4; q++)
      #pragma unroll
      for (int j = 0; j < 4; j++)
        br[q*4 + j] = biash[(long)(m0 + 4*lg + 8*q + j)*1024 + col];

    if (tt < NT - 1){
      const int nb = cb ^ 1;
      #pragma unroll
      for (int i = 0; i < 8; i++){
        int row = w*16 + i*2 + rr;
        glds16(kbase + (long)((tt+1)*64 + row)*8192 + (slot ^ (row & 31))*8,
               &Ks[nb][(w*16 + i*2)*256]);
      }
    }

    // 4 accumulator chains (4 dependent MFMAs each) for ILP
    v16f a[4];
    #pragma unroll
    for (int c = 0; c < 4; c++)
      #pragma unroll
      for (int i = 0; i < 16; i++) a[c][i] = 0.f;
    #pragma unroll
    for (int kb = 0; kb < 16; kb++){
      // B-frag: key row (kh*32 + ln) of tile; LDS XOR key = row & 31 = ln
      v8bf kf8 = *(const v8bf*)&Ks[cb][(kh*32 + ln)*256 + ((2*kb + lg) ^ ln)*8];
      a[kb & 3] = __builtin_amdgcn_mfma_f32_32x32x16_bf16(qf[kb], kf8, a[kb & 3], 0, 0, 0);
    }

    #pragma unroll
    for (int q = 0; q < 4; q++){
      #pragma unroll
      for (int j = 0; j < 4; j++){
        int i = q*4 + j;
        int r = 4*lg + 8*q + j;
        float e = __expf((a[0][i] + a[1][i]) + (a[2][i] + a[3][i]) + br[i]);
        sm[i] += e;
        Eb[(long)(m0 + r)*1024 + col] = f2bf(e);
      }
    }
  }

  // reduce across the wave's 32 key-lanes
  #pragma unroll
  for (int i = 0; i < 16; i++){
    #pragma unroll
    for (int d = 1; d < 32; d <<= 1) sm[i] += __shfl_xor(sm[i], d, 64);
  }
  if (ln == 0){
    float* sp = psums + ((long)bh * KSPLIT + kh)*1024 + m0 + 4*lg;
    #pragma unroll
    for (int q = 0; q < 4; q++)
      #pragma unroll
      for (int j = 0; j < 4; j++)
        sp[8*q + j] = sm[q*4 + j];
  }
}

extern "C" void kernel_launch(void* const* d_in, const int* in_sizes, int n_in,
                              void* d_out, int out_size, void* d_ws, size_t ws_size,
                              hipStream_t stream)
{
  const float* x        = (const float*)d_in[0];
  const float* qkv_w    = (const float*)d_in[1];
  const float* qg       = (const float*)d_in[2];
  const float* qb       = (const float*)d_in[3];
  const float* qm       = (const float*)d_in[4];
  const float* qv       = (const float*)d_in[5];
  const float* pos_bias = (const float*)d_in[6];
  const float* pw       = (const float*)d_in[7];
  const float* pg       = (const float*)d_in[8];
  const float* pbt      = (const float*)d_in[9];
  const float* pmn      = (const float*)d_in[10];
  const float* pvr      = (const float*)d_in[11];
  float* out = (float*)d_out;

  // ---- adaptive workspace: FIXED 16.85MB + G*43.55MB (outc/partials overlaid) ----
  const unsigned long FIXED = 16846848UL;
  const unsigned long PERG  = 43548672UL;
  long G = 1;
  if      (ws_size >= FIXED + PERG*16) G = 16;
  else if (ws_size >= FIXED + PERG*8)  G = 8;
  else if (ws_size >= FIXED + PERG*4)  G = 4;
  else if (ws_size >= FIXED + PERG*2)  G = 2;
  else if (ws_size >= FIXED + PERG)    G = 1;
  else return;

  char* ws = (char*)d_ws;
  unsigned short* wqb = (unsigned short*)(ws + 0L);            // 12,582,912
  unsigned short* wpb = (unsigned short*)(ws + 12582912L);     //  4,194,304
  float* sc_qkv       = (float*)(ws + 16777216L);              //     32,768
  float* sh_qkv       = (float*)(ws + 16809984L);              //     32,768
  float* sc_p         = (float*)(ws + 16842752L);              //      2,048
  float* sh_p         = (float*)(ws + 16844800L);              //      2,048
  const long gb = 16846848L;
  unsigned short* xbg   = (unsigned short*)(ws + gb);                      // G*1,572,864
  unsigned short* qkvg  = (unsigned short*)(ws + gb + G*1572864L);         // G*16,777,216
  unsigned short* Vtg   = (unsigned short*)(ws + gb + G*18350080L);        // G*8,388,608
  unsigned short* Eg    = (unsigned short*)(ws + gb + G*26738688L);        // G*16,777,216
  float* sumsg          = (float*)(ws + gb + G*43515904L);                 // G*32,768 (unused)
  // overlays (dead-buffer reuse):
  unsigned short* outcg = qkvg;                 // qkv region dead after attn
  float* partials       = (float*)Eg;           // E region dead after PV
  float* psums          = (float*)xbg;          // x-bf16 region dead after qkv GEMM
                                                // needs G*8*KSPLIT*1024*4 = G*64KB <= G*1.5MB
  (void)sumsg;

  // weights + BN affines (once)
  cast_bf16_kernel<<<dim3(3072), 256, 0, stream>>>(qkv_w, wqb, 786432);
  cast_bf16_kernel<<<dim3(1024), 256, 0, stream>>>(pw,    wpb, 262144);
  bn_precompute<<<dim3(32), 256, 0, stream>>>(qg, qb, qm, qv, sc_qkv, sh_qkv, 8192, 1);
  bn_precompute<<<dim3(2),  256, 0, stream>>>(pg, pbt, pmn, pvr, sc_p, sh_p, 512, 0);

  const int nG = (int)(16 / G);
  for (int g = 0; g < nG; g++){
    const float* xg = x + (long)g * G * 786432L;
    long mbase = (long)g * G * 1024L;

    cast_bf16_kernel<<<dim3((unsigned)(G*384)), 256, 0, stream>>>(xg, xbg, (int)(G*98304));

    // qkv = BN(x @ qkv_w^T) -> Q/K row-major [G*1024][8192]; V transposed -> Vt
    gemm_nt<0><<<dim3(64, (unsigned)(8*G), 1), 256, 0, stream>>>(
        xbg, wqb, 768, 0L, 0L, 0L, sc_qkv, sh_qkv, nullptr, qkvg, nullptr, Vtg);

    // E = exp(QK^T + bias), per-key-half rowsums (4-wave blocks, XCD-swizzled)
    attn_scores<<<dim3(16, (unsigned)(8*G)), 256, 0, stream>>>(
        qkvg, pos_bias, Eg, psums);

    // outc = clamp((E @ V) / sum, -1, 1)  (overlays qkv region; XCD-swizzled)
    gemm_nt<1><<<dim3(4, 8, (unsigned)(8*G)), 256, 0, stream>>>(
        Eg, Vtg, 1024, 1048576L, 524288L, 0L, nullptr, nullptr, psums, outcg, nullptr, nullptr);

    // proj split-K=4 -> fp32 partials (overlays E region)
    gemm_nt<3><<<dim3(4, (unsigned)(8*G), 4), 256, 0, stream>>>(
        outcg, wpb, 4096, 0L, 0L, (long)(G*1024), nullptr, nullptr, nullptr,
        nullptr, partials, nullptr);

    // out rows [mbase, ...) = (sum partials)*sc + sh
    reduce_bn<<<dim3((unsigned)(G*512)), 256, 0, stream>>>(
        partials, sc_p, sh_p, out, (long)(G*1024), mbase);
  }
}